// Round 5
// baseline (4070.436 us; speedup 1.0000x reference)
//
#include <hip/hip_runtime.h>

// Problem constants
#define BB 64       // batch
#define TT 512      // time steps
#define II 128      // input dim
#define HH 512      // hidden
#define CC 5        // out classes

// ---------------------------------------------------------------------------
// GEMM: out[m][n] = sum_k A[m][k] * W[n][k] + b1[n] + b2[n]
// ---------------------------------------------------------------------------
__global__ __launch_bounds__(256) void gemm_bias_kernel(
    const float* __restrict__ A, const float* __restrict__ W,
    const float* __restrict__ b1, const float* __restrict__ b2,
    float* __restrict__ out, int K)
{
    __shared__ float As[16][132];
    __shared__ float Bs[16][132];
    const int tid = threadIdx.x;
    const int bm = blockIdx.x;
    const int bn = blockIdx.y;
    const int tx = tid & 15;
    const int ty = tid >> 4;
    const int lr = tid >> 2;
    const int lk = (tid & 3) << 2;

    const float* Ab = A + (size_t)bm * 128 * K;
    const float* Wb = W + (size_t)bn * 128 * K;

    float acc[8][8];
#pragma unroll
    for (int i = 0; i < 8; ++i)
#pragma unroll
        for (int j = 0; j < 8; ++j) acc[i][j] = 0.f;

    for (int k0 = 0; k0 < K; k0 += 16) {
        float4 a0 = *(const float4*)(Ab + (size_t)lr * K + k0 + lk);
        float4 a1 = *(const float4*)(Ab + (size_t)(lr + 64) * K + k0 + lk);
        float4 w0 = *(const float4*)(Wb + (size_t)lr * K + k0 + lk);
        float4 w1 = *(const float4*)(Wb + (size_t)(lr + 64) * K + k0 + lk);
        __syncthreads();
        As[lk + 0][lr] = a0.x; As[lk + 1][lr] = a0.y; As[lk + 2][lr] = a0.z; As[lk + 3][lr] = a0.w;
        As[lk + 0][lr + 64] = a1.x; As[lk + 1][lr + 64] = a1.y; As[lk + 2][lr + 64] = a1.z; As[lk + 3][lr + 64] = a1.w;
        Bs[lk + 0][lr] = w0.x; Bs[lk + 1][lr] = w0.y; Bs[lk + 2][lr] = w0.z; Bs[lk + 3][lr] = w0.w;
        Bs[lk + 0][lr + 64] = w1.x; Bs[lk + 1][lr + 64] = w1.y; Bs[lk + 2][lr + 64] = w1.z; Bs[lk + 3][lr + 64] = w1.w;
        __syncthreads();
#pragma unroll
        for (int k = 0; k < 16; ++k) {
            float4 av0 = *(const float4*)&As[k][ty * 8];
            float4 av1 = *(const float4*)&As[k][ty * 8 + 4];
            float4 bv0 = *(const float4*)&Bs[k][tx * 8];
            float4 bv1 = *(const float4*)&Bs[k][tx * 8 + 4];
            float a[8] = {av0.x, av0.y, av0.z, av0.w, av1.x, av1.y, av1.z, av1.w};
            float b[8] = {bv0.x, bv0.y, bv0.z, bv0.w, bv1.x, bv1.y, bv1.z, bv1.w};
#pragma unroll
            for (int i = 0; i < 8; ++i)
#pragma unroll
                for (int j = 0; j < 8; ++j)
                    acc[i][j] = fmaf(a[i], b[j], acc[i][j]);
        }
    }

    const int nb = bn * 128 + tx * 8;
    float bias[8];
#pragma unroll
    for (int j = 0; j < 8; ++j) bias[j] = b1[nb + j] + b2[nb + j];
#pragma unroll
    for (int i = 0; i < 8; ++i) {
        const size_t m = (size_t)bm * 128 + ty * 8 + i;
        float4 o0 = {acc[i][0] + bias[0], acc[i][1] + bias[1], acc[i][2] + bias[2], acc[i][3] + bias[3]};
        float4 o1 = {acc[i][4] + bias[4], acc[i][5] + bias[5], acc[i][6] + bias[6], acc[i][7] + bias[7]};
        *(float4*)(out + m * HH + nb) = o0;
        *(float4*)(out + m * HH + nb + 4) = o1;
    }
}

// ---------------------------------------------------------------------------
// Recurrent scan. 256 blocks x 512 threads. blockIdx = s*32 + g.
// R5 changes vs R4 (same row/kseg compute layout, same phase protocol):
//  - 8-byte packets: hbuf[g][slot][row] = uint64(batch0|batch1), phase bit in
//    each half's sign. 1 store/publisher, 1 load+1 vmcnt wait/poller.
//  - SELF-BYPASS: producer lanes ds_write their hn into next LDS buffer; wave
//    s (whose poll targets are all self-rows) skips polling -> self LLC RT off
//    the critical path; barrier waits only on foreign polls.
//  - SLACK ZONE: y stores + xp prefetch AFTER the poll loop (sched_barrier
//    fence against hoisting), xp prefetched TWO steps ahead -> HBM latency
//    never sits inside the poll's in-order vmcnt drain (R4's big parasite).
// ---------------------------------------------------------------------------
__global__ __launch_bounds__(512)
__attribute__((amdgpu_waves_per_eu(2, 2)))
void scan_kernel(
    const float* __restrict__ xp, const float* __restrict__ Whh,
    float* __restrict__ y, unsigned long long* hbuf)
{
    __shared__ float hbs[2][2][8 * 68];   // [buf][batch][kseg*68 + m] (+4 pad/chunk)

    const int tid  = threadIdx.x;
    const int s    = blockIdx.x >> 5;      // slice 0..7 (rows s*64..s*64+63)
    const int g    = blockIdx.x & 31;      // group 0..31 (batches 2g, 2g+1)
    const int lane = tid & 63;
    const int wv   = tid >> 6;             // wave 0..7
    const int rloc = lane >> 3;            // 0..7: local row within wave
    const int kseg = lane & 7;             // 0..7: 64-wide k-segment
    const int R    = s * 64 + wv * 8 + rloc;   // global row this lane computes

    // --- W row R, k-range kseg*64..+64: 16 explicit float4 (VGPR-resident) ---
    const float* wr = Whh + (size_t)R * HH + kseg * 64;
    const float4 w0  = *(const float4*)(wr + 0);
    const float4 w1  = *(const float4*)(wr + 4);
    const float4 w2  = *(const float4*)(wr + 8);
    const float4 w3  = *(const float4*)(wr + 12);
    const float4 w4  = *(const float4*)(wr + 16);
    const float4 w5  = *(const float4*)(wr + 20);
    const float4 w6  = *(const float4*)(wr + 24);
    const float4 w7  = *(const float4*)(wr + 28);
    const float4 w8  = *(const float4*)(wr + 32);
    const float4 w9  = *(const float4*)(wr + 36);
    const float4 w10 = *(const float4*)(wr + 40);
    const float4 w11 = *(const float4*)(wr + 44);
    const float4 w12 = *(const float4*)(wr + 48);
    const float4 w13 = *(const float4*)(wr + 52);
    const float4 w14 = *(const float4*)(wr + 56);
    const float4 w15 = *(const float4*)(wr + 60);

    unsigned long long* gbase = hbuf + (size_t)g * 1024;   // [slot 0/1][512 packets]
    const int gb0 = g * 2, gb1 = g * 2 + 1;

    const int lds_w    = wv * 68 + lane;            // poller's LDS index (chunk wv)
    const int self_lds = s * 68 + wv * 8 + rloc;    // producer's self-write index
    const bool pub     = (kseg == 0);
    const bool foreign = (wv != s);                 // this thread polls packet `tid`

    hbs[0][0][lds_w] = 0.f;
    hbs[0][1][lds_w] = 0.f;

    // xp prefetched TWO steps ahead: xpa = step t, xpb = step t+1
    float xpa0 = 0.f, xpa1 = 0.f, xpb0 = 0.f, xpb1 = 0.f;
    if (pub) {
        xpa0 = xp[(size_t)gb0 * TT * HH + R];
        xpa1 = xp[(size_t)gb1 * TT * HH + R];
        xpb0 = xp[((size_t)gb0 * TT + 1) * HH + R];
        xpb1 = xp[((size_t)gb1 * TT + 1) * HH + R];
    }
    __syncthreads();

    for (int t = 0; t < TT; ++t) {
        const int p = t & 1;

        // --- full dot product for row R over this lane's k-segment ---
        float a0 = 0.f, a1 = 0.f, c0 = 0.f, c1 = 0.f;
        const float* h0p = &hbs[p][0][kseg * 68];
        const float* h1p = &hbs[p][1][kseg * 68];
#define STEP4(WQ, OFF)                                                   \
        {                                                                \
            float4 h0 = *(const float4*)(h0p + (OFF));                   \
            float4 h1 = *(const float4*)(h1p + (OFF));                   \
            a0 = fmaf(WQ.x, h0.x, a0); a1 = fmaf(WQ.y, h0.y, a1);        \
            a0 = fmaf(WQ.z, h0.z, a0); a1 = fmaf(WQ.w, h0.w, a1);        \
            c0 = fmaf(WQ.x, h1.x, c0); c1 = fmaf(WQ.y, h1.y, c1);        \
            c0 = fmaf(WQ.z, h1.z, c0); c1 = fmaf(WQ.w, h1.w, c1);        \
        }
        STEP4(w0, 0)   STEP4(w1, 4)   STEP4(w2, 8)   STEP4(w3, 12)
        STEP4(w4, 16)  STEP4(w5, 20)  STEP4(w6, 24)  STEP4(w7, 28)
        STEP4(w8, 32)  STEP4(w9, 36)  STEP4(w10, 40) STEP4(w11, 44)
        STEP4(w12, 48) STEP4(w13, 52) STEP4(w14, 56) STEP4(w15, 60)
#undef STEP4

        // --- butterfly reduce over kseg lanes (xor 1,2,4) ---
        float A = a0 + a1, Bv = c0 + c1;
        A  += __shfl_xor(A, 1);  A  += __shfl_xor(A, 2);  A  += __shfl_xor(A, 4);
        Bv += __shfl_xor(Bv, 1); Bv += __shfl_xor(Bv, 2); Bv += __shfl_xor(Bv, 4);

        const int q = t + 1;                           // packet index
        unsigned long long* slotp = gbase + (q & 1) * 512;
        const unsigned int phase = (unsigned int)(((q + 1) >> 1) & 1);

        float hn0 = 0.f, hn1 = 0.f;
        if (pub) {
            hn0 = fmaxf(A + xpa0, 0.f);
            hn1 = fmaxf(Bv + xpa1, 0.f);
            if (q < TT) {
                const unsigned long long pkt =
                    (unsigned long long)(__float_as_uint(hn0) | (phase << 31)) |
                    ((unsigned long long)(__float_as_uint(hn1) | (phase << 31)) << 32);
                __hip_atomic_store(slotp + R, pkt,
                                   __ATOMIC_RELAXED, __HIP_MEMORY_SCOPE_AGENT);
            }
            // self-bypass: own rows go straight to LDS (never polled)
            hbs[q & 1][0][self_lds] = hn0;
            hbs[q & 1][1][self_lds] = hn1;
        }

        if (foreign && q < TT) {
            // poll own packet (row tid): payload==flag, both halves
            unsigned long long u;
            for (;;) {
                u = __hip_atomic_load(slotp + tid, __ATOMIC_RELAXED, __HIP_MEMORY_SCOPE_AGENT);
                if ((((unsigned int)(u >> 31) & 1u) == phase) &&
                    ((unsigned int)(u >> 63) == phase)) break;
            }
            hbs[q & 1][0][lds_w] = __uint_as_float((unsigned int)u & 0x7fffffffu);
            hbs[q & 1][1][lds_w] = __uint_as_float((unsigned int)(u >> 32) & 0x7fffffffu);
        }

        // fence: keep the slack-zone vmem BELOW the poll loop
        __builtin_amdgcn_sched_barrier(0);

        // --- slack zone: acks/latency covered by next compute phase ---
        if (pub) {
            y[((size_t)gb0 * TT + t) * HH + R] = hn0;
            y[((size_t)gb1 * TT + t) * HH + R] = hn1;
            xpa0 = xpb0; xpa1 = xpb1;
            if (t + 2 < TT) {
                xpb0 = xp[((size_t)gb0 * TT + t + 2) * HH + R];
                xpb1 = xp[((size_t)gb1 * TT + t + 2) * HH + R];
            }
        }
        __syncthreads();                               // the ONLY barrier/step
    }
}

// ---------------------------------------------------------------------------
// Head: out[b][c] = sum_h y[b][T-1][h] * W_out[c][h] + b_out[c]
// ---------------------------------------------------------------------------
__global__ __launch_bounds__(64) void head_kernel(
    const float* __restrict__ y2, const float* __restrict__ Wout,
    const float* __restrict__ bout, float* __restrict__ out)
{
    const int bc = blockIdx.x;
    const int b = bc / CC, c = bc % CC;
    const int lane = threadIdx.x;
    const float* yrow = y2 + ((size_t)b * TT + (TT - 1)) * HH;
    const float* wrow = Wout + (size_t)c * HH;
    float s = 0.f;
#pragma unroll
    for (int i = 0; i < HH / 64; ++i)
        s = fmaf(yrow[lane + 64 * i], wrow[lane + 64 * i], s);
#pragma unroll
    for (int off = 32; off > 0; off >>= 1) s += __shfl_down(s, off);
    if (lane == 0) out[bc] = s + bout[c];
}

// ---------------------------------------------------------------------------
extern "C" void kernel_launch(void* const* d_in, const int* in_sizes, int n_in,
                              void* d_out, int out_size, void* d_ws, size_t ws_size,
                              hipStream_t stream)
{
    const float* x = (const float*)d_in[0];
    const float* W_ih[3] = {(const float*)d_in[1], (const float*)d_in[5], (const float*)d_in[9]};
    const float* W_hh[3] = {(const float*)d_in[2], (const float*)d_in[6], (const float*)d_in[10]};
    const float* b_ih[3] = {(const float*)d_in[3], (const float*)d_in[7], (const float*)d_in[11]};
    const float* b_hh[3] = {(const float*)d_in[4], (const float*)d_in[8], (const float*)d_in[12]};
    const float* W_out = (const float*)d_in[13];
    const float* b_out = (const float*)d_in[14];
    float* out = (float*)d_out;

    // workspace layout (floats): Y, XP, hbuf
    float* ws   = (float*)d_ws;
    float* Y    = ws;                        // B*T*H
    float* XP   = ws + (size_t)BB * TT * HH; // B*T*H
    unsigned long long* hbuf = (unsigned long long*)(XP + (size_t)BB * TT * HH); // 32*2*512 packets

    const size_t hbuf_bytes = 32 * 2 * 512 * sizeof(unsigned long long);  // 256 KB
    const dim3 ggrid(256, 4, 1);

    // layer 0
    gemm_bias_kernel<<<ggrid, 256, 0, stream>>>(x, W_ih[0], b_ih[0], b_hh[0], XP, II);
    hipMemsetAsync(hbuf, 0, hbuf_bytes, stream);     // phase-clean slate per layer
    scan_kernel<<<256, 512, 0, stream>>>(XP, W_hh[0], Y, hbuf);
    // layer 1
    gemm_bias_kernel<<<ggrid, 256, 0, stream>>>(Y, W_ih[1], b_ih[1], b_hh[1], XP, HH);
    hipMemsetAsync(hbuf, 0, hbuf_bytes, stream);
    scan_kernel<<<256, 512, 0, stream>>>(XP, W_hh[1], Y, hbuf);
    // layer 2
    gemm_bias_kernel<<<ggrid, 256, 0, stream>>>(Y, W_ih[2], b_ih[2], b_hh[2], XP, HH);
    hipMemsetAsync(hbuf, 0, hbuf_bytes, stream);
    scan_kernel<<<256, 512, 0, stream>>>(XP, W_hh[2], Y, hbuf);
    // head
    head_kernel<<<BB * CC, 64, 0, stream>>>(Y, W_out, b_out, out);
}

// Round 6
// 3193.767 us; speedup vs baseline: 1.2745x; 1.2745x over previous
//
#include <hip/hip_runtime.h>

// Problem constants
#define BB 64       // batch
#define TT 512      // time steps
#define II 128      // input dim
#define HH 512      // hidden
#define CC 5        // out classes

// ---------------------------------------------------------------------------
// GEMM: out[m][n] = sum_k A[m][k] * W[n][k] + b1[n] + b2[n]
// ---------------------------------------------------------------------------
__global__ __launch_bounds__(256) void gemm_bias_kernel(
    const float* __restrict__ A, const float* __restrict__ W,
    const float* __restrict__ b1, const float* __restrict__ b2,
    float* __restrict__ out, int K)
{
    __shared__ float As[16][132];
    __shared__ float Bs[16][132];
    const int tid = threadIdx.x;
    const int bm = blockIdx.x;
    const int bn = blockIdx.y;
    const int tx = tid & 15;
    const int ty = tid >> 4;
    const int lr = tid >> 2;
    const int lk = (tid & 3) << 2;

    const float* Ab = A + (size_t)bm * 128 * K;
    const float* Wb = W + (size_t)bn * 128 * K;

    float acc[8][8];
#pragma unroll
    for (int i = 0; i < 8; ++i)
#pragma unroll
        for (int j = 0; j < 8; ++j) acc[i][j] = 0.f;

    for (int k0 = 0; k0 < K; k0 += 16) {
        float4 a0 = *(const float4*)(Ab + (size_t)lr * K + k0 + lk);
        float4 a1 = *(const float4*)(Ab + (size_t)(lr + 64) * K + k0 + lk);
        float4 w0 = *(const float4*)(Wb + (size_t)lr * K + k0 + lk);
        float4 w1 = *(const float4*)(Wb + (size_t)(lr + 64) * K + k0 + lk);
        __syncthreads();
        As[lk + 0][lr] = a0.x; As[lk + 1][lr] = a0.y; As[lk + 2][lr] = a0.z; As[lk + 3][lr] = a0.w;
        As[lk + 0][lr + 64] = a1.x; As[lk + 1][lr + 64] = a1.y; As[lk + 2][lr + 64] = a1.z; As[lk + 3][lr + 64] = a1.w;
        Bs[lk + 0][lr] = w0.x; Bs[lk + 1][lr] = w0.y; Bs[lk + 2][lr] = w0.z; Bs[lk + 3][lr] = w0.w;
        Bs[lk + 0][lr + 64] = w1.x; Bs[lk + 1][lr + 64] = w1.y; Bs[lk + 2][lr + 64] = w1.z; Bs[lk + 3][lr + 64] = w1.w;
        __syncthreads();
#pragma unroll
        for (int k = 0; k < 16; ++k) {
            float4 av0 = *(const float4*)&As[k][ty * 8];
            float4 av1 = *(const float4*)&As[k][ty * 8 + 4];
            float4 bv0 = *(const float4*)&Bs[k][tx * 8];
            float4 bv1 = *(const float4*)&Bs[k][tx * 8 + 4];
            float a[8] = {av0.x, av0.y, av0.z, av0.w, av1.x, av1.y, av1.z, av1.w};
            float b[8] = {bv0.x, bv0.y, bv0.z, bv0.w, bv1.x, bv1.y, bv1.z, bv1.w};
#pragma unroll
            for (int i = 0; i < 8; ++i)
#pragma unroll
                for (int j = 0; j < 8; ++j)
                    acc[i][j] = fmaf(a[i], b[j], acc[i][j]);
        }
    }

    const int nb = bn * 128 + tx * 8;
    float bias[8];
#pragma unroll
    for (int j = 0; j < 8; ++j) bias[j] = b1[nb + j] + b2[nb + j];
#pragma unroll
    for (int i = 0; i < 8; ++i) {
        const size_t m = (size_t)bm * 128 + ty * 8 + i;
        float4 o0 = {acc[i][0] + bias[0], acc[i][1] + bias[1], acc[i][2] + bias[2], acc[i][3] + bias[3]};
        float4 o1 = {acc[i][4] + bias[4], acc[i][5] + bias[5], acc[i][6] + bias[6], acc[i][7] + bias[7]};
        *(float4*)(out + m * HH + nb) = o0;
        *(float4*)(out + m * HH + nb + 4) = o1;
    }
}

// ---------------------------------------------------------------------------
// Recurrent scan. 256 blocks x 512 threads. blockIdx = s*32 + g.
// R6 = R4 issue-order + R5 packet format:
//  - 8-byte packets (batch0|batch1, phase bit in each half's sign bit).
//  - self-bypass: producer lanes ds_write own rows into next LDS buffer; wave
//    s skips polling (its targets are all self-rows) -> self LLC RT off path.
//  - R4 ORDERING (the R5 lesson): ALL slack vmem (y stores, xp prefetch) is
//    issued BEFORE the poll loop, so it drains inside the poll's vmcnt wait,
//    overlapped with foreign-packet flight. R5 put it after the poll and the
//    barrier's vmcnt(0) drain exposed the full HBM latency -> 1.5x regression.
//    No sched_barrier: let the compiler schedule.
// Protocol: payload-is-the-flag, phase ((q+1)>>1)&1 of packet q in slot q&1,
// relaxed agent-scope ops; hbuf memset per layer keeps phases clean.
// ---------------------------------------------------------------------------
__global__ __launch_bounds__(512)
__attribute__((amdgpu_waves_per_eu(2, 2)))
void scan_kernel(
    const float* __restrict__ xp, const float* __restrict__ Whh,
    float* __restrict__ y, unsigned long long* hbuf)
{
    __shared__ float hbs[2][2][8 * 68];   // [buf][batch][kseg*68 + m] (+4 pad/chunk)

    const int tid  = threadIdx.x;
    const int s    = blockIdx.x >> 5;      // slice 0..7 (rows s*64..s*64+63)
    const int g    = blockIdx.x & 31;      // group 0..31 (batches 2g, 2g+1)
    const int lane = tid & 63;
    const int wv   = tid >> 6;             // wave 0..7
    const int rloc = lane >> 3;            // 0..7: local row within wave
    const int kseg = lane & 7;             // 0..7: 64-wide k-segment
    const int R    = s * 64 + wv * 8 + rloc;   // global row this lane computes

    // --- W row R, k-range kseg*64..+64: 16 explicit float4 (VGPR-resident) ---
    const float* wr = Whh + (size_t)R * HH + kseg * 64;
    const float4 w0  = *(const float4*)(wr + 0);
    const float4 w1  = *(const float4*)(wr + 4);
    const float4 w2  = *(const float4*)(wr + 8);
    const float4 w3  = *(const float4*)(wr + 12);
    const float4 w4  = *(const float4*)(wr + 16);
    const float4 w5  = *(const float4*)(wr + 20);
    const float4 w6  = *(const float4*)(wr + 24);
    const float4 w7  = *(const float4*)(wr + 28);
    const float4 w8  = *(const float4*)(wr + 32);
    const float4 w9  = *(const float4*)(wr + 36);
    const float4 w10 = *(const float4*)(wr + 40);
    const float4 w11 = *(const float4*)(wr + 44);
    const float4 w12 = *(const float4*)(wr + 48);
    const float4 w13 = *(const float4*)(wr + 52);
    const float4 w14 = *(const float4*)(wr + 56);
    const float4 w15 = *(const float4*)(wr + 60);

    unsigned long long* gbase = hbuf + (size_t)g * 1024;   // [slot 0/1][512 packets]
    const int gb0 = g * 2, gb1 = g * 2 + 1;

    const int lds_w    = wv * 68 + lane;            // poller's LDS index (chunk wv)
    const int self_lds = s * 68 + wv * 8 + rloc;    // producer's self-write index
    const bool pub     = (kseg == 0);
    const bool foreign = (wv != s);                 // this thread polls packet `tid`

    hbs[0][0][lds_w] = 0.f;
    hbs[0][1][lds_w] = 0.f;

    float xp0 = 0.f, xp1 = 0.f;
    if (pub) {
        xp0 = xp[(size_t)gb0 * TT * HH + R];
        xp1 = xp[(size_t)gb1 * TT * HH + R];
    }
    __syncthreads();

    for (int t = 0; t < TT; ++t) {
        const int p = t & 1;

        // --- full dot product for row R over this lane's k-segment ---
        float a0 = 0.f, a1 = 0.f, c0 = 0.f, c1 = 0.f;
        const float* h0p = &hbs[p][0][kseg * 68];
        const float* h1p = &hbs[p][1][kseg * 68];
#define STEP4(WQ, OFF)                                                   \
        {                                                                \
            float4 h0 = *(const float4*)(h0p + (OFF));                   \
            float4 h1 = *(const float4*)(h1p + (OFF));                   \
            a0 = fmaf(WQ.x, h0.x, a0); a1 = fmaf(WQ.y, h0.y, a1);        \
            a0 = fmaf(WQ.z, h0.z, a0); a1 = fmaf(WQ.w, h0.w, a1);        \
            c0 = fmaf(WQ.x, h1.x, c0); c1 = fmaf(WQ.y, h1.y, c1);        \
            c0 = fmaf(WQ.z, h1.z, c0); c1 = fmaf(WQ.w, h1.w, c1);        \
        }
        STEP4(w0, 0)   STEP4(w1, 4)   STEP4(w2, 8)   STEP4(w3, 12)
        STEP4(w4, 16)  STEP4(w5, 20)  STEP4(w6, 24)  STEP4(w7, 28)
        STEP4(w8, 32)  STEP4(w9, 36)  STEP4(w10, 40) STEP4(w11, 44)
        STEP4(w12, 48) STEP4(w13, 52) STEP4(w14, 56) STEP4(w15, 60)
#undef STEP4

        // --- butterfly reduce over kseg lanes (xor 1,2,4) ---
        float A = a0 + a1, Bv = c0 + c1;
        A  += __shfl_xor(A, 1);  A  += __shfl_xor(A, 2);  A  += __shfl_xor(A, 4);
        Bv += __shfl_xor(Bv, 1); Bv += __shfl_xor(Bv, 2); Bv += __shfl_xor(Bv, 4);

        const int q = t + 1;                           // packet index
        unsigned long long* slotp = gbase + (q & 1) * 512;
        const unsigned int phase = (unsigned int)(((q + 1) >> 1) & 1);

        if (pub) {
            const float hn0 = fmaxf(A + xp0, 0.f);
            const float hn1 = fmaxf(Bv + xp1, 0.f);
            if (q < TT) {
                const unsigned long long pkt =
                    (unsigned long long)(__float_as_uint(hn0) | (phase << 31)) |
                    ((unsigned long long)(__float_as_uint(hn1) | (phase << 31)) << 32);
                __hip_atomic_store(slotp + R, pkt,
                                   __ATOMIC_RELAXED, __HIP_MEMORY_SCOPE_AGENT);
            }
            // self-bypass: own rows straight to LDS (never polled)
            hbs[q & 1][0][self_lds] = hn0;
            hbs[q & 1][1][self_lds] = hn1;
            // slack vmem BEFORE the poll: drains inside the poll's vmcnt wait,
            // overlapped with foreign-packet flight (R4 ordering).
            y[((size_t)gb0 * TT + t) * HH + R] = hn0;
            y[((size_t)gb1 * TT + t) * HH + R] = hn1;
            if (q < TT) {
                xp0 = xp[((size_t)gb0 * TT + q) * HH + R];
                xp1 = xp[((size_t)gb1 * TT + q) * HH + R];
            }
        }

        if (foreign && q < TT) {
            // poll own packet (row tid): payload==flag, both halves
            unsigned long long u;
            for (;;) {
                u = __hip_atomic_load(slotp + tid, __ATOMIC_RELAXED, __HIP_MEMORY_SCOPE_AGENT);
                if ((((unsigned int)(u >> 31) & 1u) == phase) &&
                    ((unsigned int)(u >> 63) == phase)) break;
            }
            hbs[q & 1][0][lds_w] = __uint_as_float((unsigned int)u & 0x7fffffffu);
            hbs[q & 1][1][lds_w] = __uint_as_float((unsigned int)(u >> 32) & 0x7fffffffu);
        }
        __syncthreads();                               // the ONLY barrier/step
    }
}

// ---------------------------------------------------------------------------
// Head: out[b][c] = sum_h y[b][T-1][h] * W_out[c][h] + b_out[c]
// ---------------------------------------------------------------------------
__global__ __launch_bounds__(64) void head_kernel(
    const float* __restrict__ y2, const float* __restrict__ Wout,
    const float* __restrict__ bout, float* __restrict__ out)
{
    const int bc = blockIdx.x;
    const int b = bc / CC, c = bc % CC;
    const int lane = threadIdx.x;
    const float* yrow = y2 + ((size_t)b * TT + (TT - 1)) * HH;
    const float* wrow = Wout + (size_t)c * HH;
    float s = 0.f;
#pragma unroll
    for (int i = 0; i < HH / 64; ++i)
        s = fmaf(yrow[lane + 64 * i], wrow[lane + 64 * i], s);
#pragma unroll
    for (int off = 32; off > 0; off >>= 1) s += __shfl_down(s, off);
    if (lane == 0) out[bc] = s + bout[c];
}

// ---------------------------------------------------------------------------
extern "C" void kernel_launch(void* const* d_in, const int* in_sizes, int n_in,
                              void* d_out, int out_size, void* d_ws, size_t ws_size,
                              hipStream_t stream)
{
    const float* x = (const float*)d_in[0];
    const float* W_ih[3] = {(const float*)d_in[1], (const float*)d_in[5], (const float*)d_in[9]};
    const float* W_hh[3] = {(const float*)d_in[2], (const float*)d_in[6], (const float*)d_in[10]};
    const float* b_ih[3] = {(const float*)d_in[3], (const float*)d_in[7], (const float*)d_in[11]};
    const float* b_hh[3] = {(const float*)d_in[4], (const float*)d_in[8], (const float*)d_in[12]};
    const float* W_out = (const float*)d_in[13];
    const float* b_out = (const float*)d_in[14];
    float* out = (float*)d_out;

    // workspace layout (floats): Y, XP, hbuf
    float* ws   = (float*)d_ws;
    float* Y    = ws;                        // B*T*H
    float* XP   = ws + (size_t)BB * TT * HH; // B*T*H
    unsigned long long* hbuf = (unsigned long long*)(XP + (size_t)BB * TT * HH); // 32*2*512 packets

    const size_t hbuf_bytes = 32 * 2 * 512 * sizeof(unsigned long long);  // 256 KB
    const dim3 ggrid(256, 4, 1);

    // layer 0
    gemm_bias_kernel<<<ggrid, 256, 0, stream>>>(x, W_ih[0], b_ih[0], b_hh[0], XP, II);
    hipMemsetAsync(hbuf, 0, hbuf_bytes, stream);     // phase-clean slate per layer
    scan_kernel<<<256, 512, 0, stream>>>(XP, W_hh[0], Y, hbuf);
    // layer 1
    gemm_bias_kernel<<<ggrid, 256, 0, stream>>>(Y, W_ih[1], b_ih[1], b_hh[1], XP, HH);
    hipMemsetAsync(hbuf, 0, hbuf_bytes, stream);
    scan_kernel<<<256, 512, 0, stream>>>(XP, W_hh[1], Y, hbuf);
    // layer 2
    gemm_bias_kernel<<<ggrid, 256, 0, stream>>>(Y, W_ih[2], b_ih[2], b_hh[2], XP, HH);
    hipMemsetAsync(hbuf, 0, hbuf_bytes, stream);
    scan_kernel<<<256, 512, 0, stream>>>(XP, W_hh[2], Y, hbuf);
    // head
    head_kernel<<<BB * CC, 64, 0, stream>>>(Y, W_out, b_out, out);
}

// Round 8
// 2687.764 us; speedup vs baseline: 1.5144x; 1.1883x over previous
//
#include <hip/hip_runtime.h>

// Problem constants
#define BB 64       // batch
#define TT 512      // time steps
#define II 128      // input dim
#define HH 512      // hidden
#define CC 5        // out classes

// ---------------------------------------------------------------------------
// GEMM: out[m][n] = sum_k A[m][k] * W[n][k] + b1[n] + b2[n]
// ---------------------------------------------------------------------------
__global__ __launch_bounds__(256) void gemm_bias_kernel(
    const float* __restrict__ A, const float* __restrict__ W,
    const float* __restrict__ b1, const float* __restrict__ b2,
    float* __restrict__ out, int K)
{
    __shared__ float As[16][132];
    __shared__ float Bs[16][132];
    const int tid = threadIdx.x;
    const int bm = blockIdx.x;
    const int bn = blockIdx.y;
    const int tx = tid & 15;
    const int ty = tid >> 4;
    const int lr = tid >> 2;
    const int lk = (tid & 3) << 2;

    const float* Ab = A + (size_t)bm * 128 * K;
    const float* Wb = W + (size_t)bn * 128 * K;

    float acc[8][8];
#pragma unroll
    for (int i = 0; i < 8; ++i)
#pragma unroll
        for (int j = 0; j < 8; ++j) acc[i][j] = 0.f;

    for (int k0 = 0; k0 < K; k0 += 16) {
        float4 a0 = *(const float4*)(Ab + (size_t)lr * K + k0 + lk);
        float4 a1 = *(const float4*)(Ab + (size_t)(lr + 64) * K + k0 + lk);
        float4 w0 = *(const float4*)(Wb + (size_t)lr * K + k0 + lk);
        float4 w1 = *(const float4*)(Wb + (size_t)(lr + 64) * K + k0 + lk);
        __syncthreads();
        As[lk + 0][lr] = a0.x; As[lk + 1][lr] = a0.y; As[lk + 2][lr] = a0.z; As[lk + 3][lr] = a0.w;
        As[lk + 0][lr + 64] = a1.x; As[lk + 1][lr + 64] = a1.y; As[lk + 2][lr + 64] = a1.z; As[lk + 3][lr + 64] = a1.w;
        Bs[lk + 0][lr] = w0.x; Bs[lk + 1][lr] = w0.y; Bs[lk + 2][lr] = w0.z; Bs[lk + 3][lr] = w0.w;
        Bs[lk + 0][lr + 64] = w1.x; Bs[lk + 1][lr + 64] = w1.y; Bs[lk + 2][lr + 64] = w1.z; Bs[lk + 3][lr + 64] = w1.w;
        __syncthreads();
#pragma unroll
        for (int k = 0; k < 16; ++k) {
            float4 av0 = *(const float4*)&As[k][ty * 8];
            float4 av1 = *(const float4*)&As[k][ty * 8 + 4];
            float4 bv0 = *(const float4*)&Bs[k][tx * 8];
            float4 bv1 = *(const float4*)&Bs[k][tx * 8 + 4];
            float a[8] = {av0.x, av0.y, av0.z, av0.w, av1.x, av1.y, av1.z, av1.w};
            float b[8] = {bv0.x, bv0.y, bv0.z, bv0.w, bv1.x, bv1.y, bv1.z, bv1.w};
#pragma unroll
            for (int i = 0; i < 8; ++i)
#pragma unroll
                for (int j = 0; j < 8; ++j)
                    acc[i][j] = fmaf(a[i], b[j], acc[i][j]);
        }
    }

    const int nb = bn * 128 + tx * 8;
    float bias[8];
#pragma unroll
    for (int j = 0; j < 8; ++j) bias[j] = b1[nb + j] + b2[nb + j];
#pragma unroll
    for (int i = 0; i < 8; ++i) {
        const size_t m = (size_t)bm * 128 + ty * 8 + i;
        float4 o0 = {acc[i][0] + bias[0], acc[i][1] + bias[1], acc[i][2] + bias[2], acc[i][3] + bias[3]};
        float4 o1 = {acc[i][4] + bias[4], acc[i][5] + bias[5], acc[i][6] + bias[6], acc[i][7] + bias[7]};
        *(float4*)(out + m * HH + nb) = o0;
        *(float4*)(out + m * HH + nb + 4) = o1;
    }
}

// ---------------------------------------------------------------------------
// Recurrent scan. 256 blocks x 512 threads. blockIdx = s*32 + g.
// R8 = R7 with compilable fences (__threadfence_block, workgroup scope).
// BARRIER-FREE wave-autonomous protocol. Roles per wave wv:
//  - computes rows R = s*64 + wv*8 + rloc (kseg k-split + shuffle reduce)
//  - pub lanes (kseg==0) publish 64-bit packets to global slot q&3 AND
//    ds_write their 8 self-rows into LDS chunk s
//  - if wv != s: polls foreign block wv's packets, ds_writes LDS chunk wv
//  - sets written[wv] = q when done; a wave starts step t by spinning until
//    all 8 written[] >= t (cheap LDS spin).
// NO per-step __syncthreads: written[c]>=t implies wave c FINISHED step t-1,
// so sibling skew <= 1 step; 4-deep LDS buffers (t&3) and 4 global slots
// (phase = 1^(((q-1)>>2)&1), memset-0 safe: first use of each slot has
// phase 1) give distance-4 clobber protection vs proven skew <=1. Cross-
// block publish spread <=1 (publish of q requires consuming all partners'
// q-1), so a poller sees only q or q-4 in a slot -- phases differ.
// Partner jitter is absorbed per-wave instead of amplified by a barrier.
// ---------------------------------------------------------------------------
__global__ __launch_bounds__(512)
__attribute__((amdgpu_waves_per_eu(2, 2)))
void scan_kernel(
    const float* __restrict__ xp, const float* __restrict__ Whh,
    float* __restrict__ y, unsigned long long* hbuf)
{
    __shared__ float hbs[4][2][8 * 68];   // [buf][batch][kseg*68 + m] (+4 pad)
    __shared__ int written[8];            // chunk/wave progress flags

    const int tid  = threadIdx.x;
    const int s    = blockIdx.x >> 5;      // slice 0..7 (rows s*64..s*64+63)
    const int g    = blockIdx.x & 31;      // group 0..31 (batches 2g, 2g+1)
    const int lane = tid & 63;
    const int wv   = tid >> 6;             // wave 0..7
    const int rloc = lane >> 3;            // 0..7: local row within wave
    const int kseg = lane & 7;             // 0..7: 64-wide k-segment
    const int R    = s * 64 + wv * 8 + rloc;   // global row this lane computes

    // --- W row R, k-range kseg*64..+64: 16 explicit float4 (VGPR-resident) ---
    const float* wr = Whh + (size_t)R * HH + kseg * 64;
    const float4 w0  = *(const float4*)(wr + 0);
    const float4 w1  = *(const float4*)(wr + 4);
    const float4 w2  = *(const float4*)(wr + 8);
    const float4 w3  = *(const float4*)(wr + 12);
    const float4 w4  = *(const float4*)(wr + 16);
    const float4 w5  = *(const float4*)(wr + 20);
    const float4 w6  = *(const float4*)(wr + 24);
    const float4 w7  = *(const float4*)(wr + 28);
    const float4 w8  = *(const float4*)(wr + 32);
    const float4 w9  = *(const float4*)(wr + 36);
    const float4 w10 = *(const float4*)(wr + 40);
    const float4 w11 = *(const float4*)(wr + 44);
    const float4 w12 = *(const float4*)(wr + 48);
    const float4 w13 = *(const float4*)(wr + 52);
    const float4 w14 = *(const float4*)(wr + 56);
    const float4 w15 = *(const float4*)(wr + 60);

    unsigned long long* gbase = hbuf + (size_t)g * 2048;   // [slot 0..3][512 packets]
    const int gb0 = g * 2, gb1 = g * 2 + 1;

    const int lds_w    = wv * 68 + lane;            // poller's LDS index (chunk wv)
    const int self_lds = s * 68 + wv * 8 + rloc;    // producer's self-write index
    const bool pub     = (kseg == 0);
    const bool foreign = (wv != s);                 // this thread polls packet `tid`

    // h_0 = 0 lives in buf 0
    hbs[0][0][lds_w] = 0.f;
    hbs[0][1][lds_w] = 0.f;
    if (tid < 8) written[tid] = 0;

    float xp0 = 0.f, xp1 = 0.f;
    if (pub) {
        xp0 = xp[(size_t)gb0 * TT * HH + R];
        xp1 = xp[(size_t)gb1 * TT * HH + R];
    }
    __syncthreads();   // one-time: LDS init visible

    for (int t = 0; t < TT; ++t) {
        // --- (A) wait for all 8 chunks of h_t (LDS spin; no barrier) ---
        if (t > 0) {
            for (;;) {
                int m = __hip_atomic_load(&written[0], __ATOMIC_RELAXED,
                                          __HIP_MEMORY_SCOPE_WORKGROUP);
#pragma unroll
                for (int c = 1; c < 8; ++c) {
                    int wc = __hip_atomic_load(&written[c], __ATOMIC_RELAXED,
                                               __HIP_MEMORY_SCOPE_WORKGROUP);
                    m = (wc < m) ? wc : m;
                }
                if (m >= t) break;
            }
            __threadfence_block();   // acquire: LDS chunk reads below stay below
        }

        // --- (B) full dot product for row R over this lane's k-segment ---
        const int bi = t & 3;
        float a0 = 0.f, a1 = 0.f, c0 = 0.f, c1 = 0.f;
        const float* h0p = &hbs[bi][0][kseg * 68];
        const float* h1p = &hbs[bi][1][kseg * 68];
#define STEP4(WQ, OFF)                                                   \
        {                                                                \
            float4 h0 = *(const float4*)(h0p + (OFF));                   \
            float4 h1 = *(const float4*)(h1p + (OFF));                   \
            a0 = fmaf(WQ.x, h0.x, a0); a1 = fmaf(WQ.y, h0.y, a1);        \
            a0 = fmaf(WQ.z, h0.z, a0); a1 = fmaf(WQ.w, h0.w, a1);        \
            c0 = fmaf(WQ.x, h1.x, c0); c1 = fmaf(WQ.y, h1.y, c1);        \
            c0 = fmaf(WQ.z, h1.z, c0); c1 = fmaf(WQ.w, h1.w, c1);        \
        }
        STEP4(w0, 0)   STEP4(w1, 4)   STEP4(w2, 8)   STEP4(w3, 12)
        STEP4(w4, 16)  STEP4(w5, 20)  STEP4(w6, 24)  STEP4(w7, 28)
        STEP4(w8, 32)  STEP4(w9, 36)  STEP4(w10, 40) STEP4(w11, 44)
        STEP4(w12, 48) STEP4(w13, 52) STEP4(w14, 56) STEP4(w15, 60)
#undef STEP4

        // --- butterfly reduce over kseg lanes (xor 1,2,4) ---
        float A = a0 + a1, Bv = c0 + c1;
        A  += __shfl_xor(A, 1);  A  += __shfl_xor(A, 2);  A  += __shfl_xor(A, 4);
        Bv += __shfl_xor(Bv, 1); Bv += __shfl_xor(Bv, 2); Bv += __shfl_xor(Bv, 4);

        const int q = t + 1;                           // packet index
        unsigned long long* slotp = gbase + (q & 3) * 512;
        const unsigned int phase = 1u ^ (((unsigned)(q - 1) >> 2) & 1u);

        float hn0 = 0.f, hn1 = 0.f;
        if (pub) {
            hn0 = fmaxf(A + xp0, 0.f);
            hn1 = fmaxf(Bv + xp1, 0.f);
            if (q < TT) {
                const unsigned long long pkt =
                    (unsigned long long)(__float_as_uint(hn0) | (phase << 31)) |
                    ((unsigned long long)(__float_as_uint(hn1) | (phase << 31)) << 32);
                __hip_atomic_store(slotp + R, pkt,
                                   __ATOMIC_RELAXED, __HIP_MEMORY_SCOPE_AGENT);
                // self-bypass: own rows straight into buf q&3 (never polled)
                hbs[q & 3][0][self_lds] = hn0;
                hbs[q & 3][1][self_lds] = hn1;
            }
            // slack vmem before the poll: overlaps foreign-packet flight
            y[((size_t)gb0 * TT + t) * HH + R] = hn0;
            y[((size_t)gb1 * TT + t) * HH + R] = hn1;
            if (q < TT) {
                xp0 = xp[((size_t)gb0 * TT + q) * HH + R];
                xp1 = xp[((size_t)gb1 * TT + q) * HH + R];
            }
        }

        if (q < TT) {
            if (foreign) {
                // poll own packet (row tid): payload==flag, both halves
                unsigned long long u;
                for (;;) {
                    u = __hip_atomic_load(slotp + tid, __ATOMIC_RELAXED,
                                          __HIP_MEMORY_SCOPE_AGENT);
                    if ((((unsigned int)(u >> 31) & 1u) == phase) &&
                        ((unsigned int)(u >> 63) == phase)) break;
                }
                hbs[q & 3][0][lds_w] = __uint_as_float((unsigned int)u & 0x7fffffffu);
                hbs[q & 3][1][lds_w] = __uint_as_float((unsigned int)(u >> 32) & 0x7fffffffu);
            }
            // --- (H) chunk wv (and this wave's self-rows) for q are done ---
            __threadfence_block();   // release: chunk writes visible before flag
            if (lane == 0)
                __hip_atomic_store(&written[wv], q, __ATOMIC_RELAXED,
                                   __HIP_MEMORY_SCOPE_WORKGROUP);
        }
    }
}

// ---------------------------------------------------------------------------
// Head: out[b][c] = sum_h y[b][T-1][h] * W_out[c][h] + b_out[c]
// ---------------------------------------------------------------------------
__global__ __launch_bounds__(64) void head_kernel(
    const float* __restrict__ y2, const float* __restrict__ Wout,
    const float* __restrict__ bout, float* __restrict__ out)
{
    const int bc = blockIdx.x;
    const int b = bc / CC, c = bc % CC;
    const int lane = threadIdx.x;
    const float* yrow = y2 + ((size_t)b * TT + (TT - 1)) * HH;
    const float* wrow = Wout + (size_t)c * HH;
    float s = 0.f;
#pragma unroll
    for (int i = 0; i < HH / 64; ++i)
        s = fmaf(yrow[lane + 64 * i], wrow[lane + 64 * i], s);
#pragma unroll
    for (int off = 32; off > 0; off >>= 1) s += __shfl_down(s, off);
    if (lane == 0) out[bc] = s + bout[c];
}

// ---------------------------------------------------------------------------
extern "C" void kernel_launch(void* const* d_in, const int* in_sizes, int n_in,
                              void* d_out, int out_size, void* d_ws, size_t ws_size,
                              hipStream_t stream)
{
    const float* x = (const float*)d_in[0];
    const float* W_ih[3] = {(const float*)d_in[1], (const float*)d_in[5], (const float*)d_in[9]};
    const float* W_hh[3] = {(const float*)d_in[2], (const float*)d_in[6], (const float*)d_in[10]};
    const float* b_ih[3] = {(const float*)d_in[3], (const float*)d_in[7], (const float*)d_in[11]};
    const float* b_hh[3] = {(const float*)d_in[4], (const float*)d_in[8], (const float*)d_in[12]};
    const float* W_out = (const float*)d_in[13];
    const float* b_out = (const float*)d_in[14];
    float* out = (float*)d_out;

    // workspace layout (floats): Y, XP, hbuf (4 slots)
    float* ws   = (float*)d_ws;
    float* Y    = ws;                        // B*T*H
    float* XP   = ws + (size_t)BB * TT * HH; // B*T*H
    unsigned long long* hbuf = (unsigned long long*)(XP + (size_t)BB * TT * HH); // 32*4*512 packets

    const size_t hbuf_bytes = 32 * 4 * 512 * sizeof(unsigned long long);  // 512 KB
    const dim3 ggrid(256, 4, 1);

    // layer 0
    gemm_bias_kernel<<<ggrid, 256, 0, stream>>>(x, W_ih[0], b_ih[0], b_hh[0], XP, II);
    (void)hipMemsetAsync(hbuf, 0, hbuf_bytes, stream);   // phase-clean slate per layer
    scan_kernel<<<256, 512, 0, stream>>>(XP, W_hh[0], Y, hbuf);
    // layer 1
    gemm_bias_kernel<<<ggrid, 256, 0, stream>>>(Y, W_ih[1], b_ih[1], b_hh[1], XP, HH);
    (void)hipMemsetAsync(hbuf, 0, hbuf_bytes, stream);
    scan_kernel<<<256, 512, 0, stream>>>(XP, W_hh[1], Y, hbuf);
    // layer 2
    gemm_bias_kernel<<<ggrid, 256, 0, stream>>>(Y, W_ih[2], b_ih[2], b_hh[2], XP, HH);
    (void)hipMemsetAsync(hbuf, 0, hbuf_bytes, stream);
    scan_kernel<<<256, 512, 0, stream>>>(XP, W_hh[2], Y, hbuf);
    // head
    head_kernel<<<BB * CC, 64, 0, stream>>>(Y, W_out, b_out, out);
}